// Round 20
// baseline (249.622 us; speedup 1.0000x reference)
//
#include <hip/hip_runtime.h>
#include <cstdint>

#define HEXP 10.0f
#define LN2 0.69314718056f
#define RLN2 1.44269504089f
#define QSCALE 500.0f

__device__ __forceinline__ float hw_log2(float x) { return __builtin_amdgcn_logf(x); }
__device__ __forceinline__ float hw_exp2(float x) { return __builtin_amdgcn_exp2f(x); }
__device__ __forceinline__ float hw_rcp(float x) { return __builtin_amdgcn_rcpf(x); }

typedef int i32x4 __attribute__((ext_vector_type(4)));

__device__ __forceinline__ void gl_lds16(const void* g, void* l) {
  __builtin_amdgcn_global_load_lds(
      (const __attribute__((address_space(1))) void*)g,
      (__attribute__((address_space(3))) void*)l, 16, 0, 0);
}

#define BAR() asm volatile("s_barrier" ::: "memory")
#define VM4() asm volatile("s_waitcnt vmcnt(4)" ::: "memory")
#define VM0() asm volatile("s_waitcnt vmcnt(0)" ::: "memory")
#define LGKM0() asm volatile("s_waitcnt lgkmcnt(0)" ::: "memory")
#define SCHED0() __builtin_amdgcn_sched_barrier(0)

// ------- row L2-normalize f32 -> int8 (x QSCALE), plain row-major (R13) -------
// |xn_i| <= ~0.17 -> q <= ~87 << 127; dot exact in int32 (<= 7.7M < 2^24).
__global__ __launch_bounds__(256) void k_rownorm(const float* __restrict__ in,
                                                 unsigned char* __restrict__ out,
                                                 int D) {
  const int row = blockIdx.x;
  const int tid = threadIdx.x;
  const float4* inr = (const float4*)(in + (size_t)row * D);
  float4 v = inr[tid];
  float ss = v.x * v.x + v.y * v.y + v.z * v.z + v.w * v.w;
#pragma unroll
  for (int off = 32; off >= 1; off >>= 1) ss += __shfl_xor(ss, off, 64);
  __shared__ float s4[4];
  if ((tid & 63) == 0) s4[tid >> 6] = ss;
  __syncthreads();
  float tot = s4[0] + s4[1] + s4[2] + s4[3];
  float scale = QSCALE / fmaxf(sqrtf(tot), 1e-12f);
  int q0 = __float2int_rn(fmaxf(-127.f, fminf(127.f, v.x * scale)));
  int q1 = __float2int_rn(fmaxf(-127.f, fminf(127.f, v.y * scale)));
  int q2 = __float2int_rn(fmaxf(-127.f, fminf(127.f, v.z * scale)));
  int q3 = __float2int_rn(fmaxf(-127.f, fminf(127.f, v.w * scale)));
  int w0 = (q0 & 0xff) | ((q1 & 0xff) << 8) | ((q2 & 0xff) << 16) | (q3 << 24);
  *(int*)(out + (size_t)row * D + tid * 4) = w0;
}

// ------- fused i8 GEMM + harmonic-softmax partials — m201 fine-phase port ----
// 256x256 tile, 8 waves (2M x 4N), per-wave 128x64 (acc[8][4] = 128 AGPR).
// m233 insight: coarse 2-segment loops cap ~25-33% MfmaUtil (R13-R19 all hit
// it); m201's fine phases measured 62% on this 8-wave/1-block geometry.
// Per K-step (BK=64), TWO phases of {ds_read frags || stage 2 gl_lds -> BAR
// -> lgkm(0) -> setprio(1) -> 16 MFMA -> setprio(0) -> BAR}: the barrier
// arrival time of the other 7 waves hides each phase's LDS latency; counted
// VM4 cert ONCE per K-step (R13's proven stage-t+2 ring-3 calendar).
//   P0: read A-frags 0..3 + B-frags 0..3 of slot t; stage A(t+2); MFMA Mg0.
//   P1: read A-frags 4..7 (bv stays in regs); stage B(t+2); VM4; MFMA Mg1.
// Cert audit: stages issued during t = [A(t+2) 2, B(t+2) 2]; at P1's VM4 the
// queue is [A(t+1) 2, B(t+1) 2, A(t+2) 2, B(t+2) 2] -> VM4 drains t+1's 4 ->
// slot (t+1)%3 certified before next iteration's P0 reads (BAR = cross-wave).
// WAR: slot (t+2)%3 = (t-1)%3, readers done at t-1's last BAR < issue. Tails:
// t=14 -> VM0 (certify t15); t=15 no stage/cert.
// Zero-conflict LDS geometry + rule-#21 staging decode: R11/R13 verbatim.
__global__ __launch_bounds__(512, 2) void k_gemm_lse(
    const unsigned char* __restrict__ xnb,
    const unsigned char* __restrict__ wnb,
    const int* __restrict__ tgt,
    float* __restrict__ parts,
    float* __restrict__ tlp,
    int M, int C, int D, int ntN) {
  __shared__ __align__(16) unsigned char sA[3][16384];  // 256r x 64k i8
  __shared__ __align__(16) unsigned char sB[3][16384];  // 256c x 64k i8
  __shared__ int s_tgt[256];

  const int ntM = M >> 8;               // 16
  const int nwg = ntM * ntN;            // 2000 (div by 8)
  const int orig = blockIdx.x;
  const int cpx = nwg >> 3;
  const int bid = (orig & 7) * cpx + (orig >> 3);   // bijective XCD swizzle
  const int tileM = bid % ntM;
  const int tileN = bid / ntM;
  const int row0 = tileM << 8;
  const int c0 = tileN << 8;

  const int tid = threadIdx.x;
  const int lane = tid & 63;
  const int wid = tid >> 6;             // 0..7
  const int wr = wid >> 2;              // M-half (128 rows)
  const int wc = wid & 3;               // N-quarter (64 cols)
  const int fcol = lane & 15;
  const int kq = lane >> 4;

  if (tid < 256) s_tgt[tid] = tgt[row0 + tid];

  // staging lane constants (rule #21 decode, R11/R13 verbatim)
  const int srow_l = lane >> 2;
  const int scol_l = (((lane & 3) ^ ((lane >> 3) & 3)) << 4);
  const int lane16 = lane << 4;
  const size_t Dz = (size_t)D;

  // wave wid stages rows [wid*32, +32) = 2 x 1KB chunks per matrix
#define STAGE_A(ds, kb)                                                        \
  do {                                                                         \
    gl_lds16(xnb + (size_t)(row0 + (wid << 5) + srow_l) * Dz + (kb) + scol_l,  \
             sA[ds] + (wid << 11) + lane16);                                   \
    gl_lds16(xnb + (size_t)(row0 + (wid << 5) + 16 + srow_l) * Dz + (kb) +     \
                 scol_l,                                                       \
             sA[ds] + (wid << 11) + 1024 + lane16);                            \
  } while (0)
#define STAGE_B(ds, kb)                                                        \
  do {                                                                         \
    gl_lds16(wnb + (size_t)(c0 + (wid << 5) + srow_l) * Dz + (kb) + scol_l,    \
             sB[ds] + (wid << 11) + lane16);                                   \
    gl_lds16(wnb + (size_t)(c0 + (wid << 5) + 16 + srow_l) * Dz + (kb) +       \
                 scol_l,                                                       \
             sB[ds] + (wid << 11) + 1024 + lane16);                            \
  } while (0)

  // fragment read bases (zero-conflict geometry, R11/R13 verbatim)
  const int slot16 = ((kq ^ ((fcol >> 1) & 3)) << 4);
  const int abase = (wr * 128 + fcol) * 64 + slot16;   // frag mm at + mm*1024
  const int bbase = (wc * 64 + fcol) * 64 + slot16;    // frag n at + n*1024

  i32x4 acc[8][4];
#pragma unroll
  for (int m = 0; m < 8; ++m)
#pragma unroll
    for (int n = 0; n < 4; ++n) acc[m][n] = (i32x4){0, 0, 0, 0};

  i32x4 av[4], bv[4];
  const int NT = D >> 6;  // 16 K-steps of 64

  // prologue: stage slots 0,1 (4 each); VM4 drains slot0 -> certified; BAR.
  STAGE_A(0, 0);
  STAGE_B(0, 0);
  STAGE_A(1, 64);
  STAGE_B(1, 64);
  VM4();
  BAR();

#pragma unroll
  for (int t = 0; t < 16; ++t) {
    const int s = t % 3;
    const unsigned char* pA = sA[s];
    const unsigned char* pB = sB[s];
    const int kb2 = (t + 2) << 6;
    // ---------------- P0: Mg0 ----------------
#pragma unroll
    for (int mm = 0; mm < 4; ++mm)
      av[mm] = *(const i32x4*)(pA + abase + mm * 1024);
#pragma unroll
    for (int n = 0; n < 4; ++n)
      bv[n] = *(const i32x4*)(pB + bbase + n * 1024);
    if (t + 2 < NT) STAGE_A((t + 2) % 3, kb2);
    BAR();
    LGKM0();
    SCHED0();
    __builtin_amdgcn_s_setprio(1);
#pragma unroll
    for (int mm = 0; mm < 4; ++mm)
#pragma unroll
      for (int n = 0; n < 4; ++n)
        acc[mm][n] = __builtin_amdgcn_mfma_i32_16x16x64_i8(av[mm], bv[n],
                                                           acc[mm][n], 0, 0, 0);
    __builtin_amdgcn_s_setprio(0);
    BAR();
    // ---------------- P1: Mg1 (bv still live in regs) ----------------
#pragma unroll
    for (int mm = 0; mm < 4; ++mm)
      av[mm] = *(const i32x4*)(pA + abase + (4 + mm) * 1024);
    if (t + 2 < NT) STAGE_B((t + 2) % 3, kb2);
    if (t + 2 < NT) VM4();        // drain slot t+1's 4; keep t+2's 4 in flight
    else if (t + 1 < NT) VM0();   // tail: certify final slot fully
    BAR();
    LGKM0();
    SCHED0();
    __builtin_amdgcn_s_setprio(1);
#pragma unroll
    for (int mm = 0; mm < 4; ++mm)
#pragma unroll
      for (int n = 0; n < 4; ++n)
        acc[4 + mm][n] = __builtin_amdgcn_mfma_i32_16x16x64_i8(
            av[mm], bv[n], acc[4 + mm][n], 0, 0, 0);
    __builtin_amdgcn_s_setprio(0);
    BAR();
  }

  // ---- epilogue: t2 = 2 - 2*dot/S^2; se-term = t2^-5 = d^-10 ----
  // C/D: col = fcol, row = kq*4 + j per 16x16 fragment.
#pragma unroll
  for (int m = 0; m < 8; ++m) {
#pragma unroll
    for (int j = 0; j < 4; ++j) {
      const int rl = wr * 128 + m * 16 + kq * 4 + j;
      const int grow = row0 + rl;
      const int trow = s_tgt[rl];
      float se = 0.f;
#pragma unroll
      for (int n = 0; n < 4; ++n) {
        float dotf = (float)acc[m][n][j];
        float t2 = fmaxf(fmaf(dotf, -2.f / (QSCALE * QSCALE), 2.f), 1e-6f);
        float r = hw_rcp(t2);
        float r2 = r * r;
        float r4 = r2 * r2;
        se += r4 * r;  // t2^-5
        int col = c0 + wc * 64 + n * 16 + fcol;
        if (col == trow) tlp[grow] = (-HEXP * LN2) * hw_log2(sqrtf(t2) + 1e-8f);
      }
#pragma unroll
      for (int off = 8; off >= 1; off >>= 1) se += __shfl_xor(se, off, 64);
      if (fcol == 0) parts[(size_t)grow * (ntN * 4) + tileN * 4 + wc] = se;
    }
  }
}

// ---------------- per-row sum of linear partials + loss ----------------
__global__ __launch_bounds__(256) void k_combine(const float* __restrict__ parts,
                                                 const float* __restrict__ tlp,
                                                 float* __restrict__ rloss, int P) {
  const int row = blockIdx.x;
  const int tid = threadIdx.x;
  const float* p = parts + (size_t)row * P;
  float s = 0.f;
  for (int i = tid; i < P; i += 256) s += p[i];
#pragma unroll
  for (int off = 32; off >= 1; off >>= 1) s += __shfl_xor(s, off, 64);
  __shared__ float ssum[4];
  if ((tid & 63) == 0) ssum[tid >> 6] = s;
  __syncthreads();
  if (tid == 0) {
    float tot = ssum[0] + ssum[1] + ssum[2] + ssum[3];
    float lse = hw_log2(tot) * LN2;
    float pt = hw_exp2((tlp[row] - lse) * RLN2);
    rloss[row] = -hw_log2(pt + 1e-8f) * LN2;
  }
}

// ---------------- mean over rows ----------------
__global__ __launch_bounds__(256) void k_mean(const float* __restrict__ rloss,
                                              float* __restrict__ out, int B) {
  const int tid = threadIdx.x;
  double s = 0.0;
  for (int i = tid; i < B; i += 256) s += (double)rloss[i];
#pragma unroll
  for (int off = 32; off >= 1; off >>= 1) s += __shfl_xor(s, off, 64);
  __shared__ double sd[4];
  if ((tid & 63) == 0) sd[tid >> 6] = s;
  __syncthreads();
  if (tid == 0) out[0] = (float)((sd[0] + sd[1] + sd[2] + sd[3]) / (double)B);
}

extern "C" void kernel_launch(void* const* d_in, const int* in_sizes, int n_in,
                              void* d_out, int out_size, void* d_ws, size_t ws_size,
                              hipStream_t stream) {
  const float* x = (const float*)d_in[0];
  const float* w = (const float*)d_in[1];
  const int* tg = (const int*)d_in[2];
  const int B = in_sizes[2];
  const int D = in_sizes[0] / B;       // 1024
  const int C = in_sizes[1] / D;       // 32000
  const int ntN = C / 256;             // 125

  char* ws = (char*)d_ws;
  unsigned char* xnb = (unsigned char*)ws;                   // B*D i8
  unsigned char* wnb = xnb + (size_t)B * D;                  // C*D i8
  size_t off = (size_t)B * D + (size_t)C * D;
  off = (off + 255) & ~(size_t)255;
  float* parts = (float*)(ws + off);                         // B * ntN * 4
  off += (size_t)B * ntN * 4 * sizeof(float);
  float* tlp = (float*)(ws + off);                           // B
  off += (size_t)B * sizeof(float);
  float* rloss = (float*)(ws + off);                         // B

  k_rownorm<<<B, 256, 0, stream>>>(x, xnb, D);
  k_rownorm<<<C, 256, 0, stream>>>(w, wnb, D);
  k_gemm_lse<<<(B / 256) * ntN, 512, 0, stream>>>(xnb, wnb, tg, parts, tlp, B, C, D, ntN);
  k_combine<<<B, 256, 0, stream>>>(parts, tlp, rloss, ntN * 4);
  k_mean<<<1, 256, 0, stream>>>(rloss, (float*)d_out, B);
}

// Round 21
// 221.984 us; speedup vs baseline: 1.1245x; 1.1245x over previous
//
#include <hip/hip_runtime.h>
#include <cstdint>

#define HEXP 10.0f
#define LN2 0.69314718056f
#define RLN2 1.44269504089f
#define QSCALE 500.0f

__device__ __forceinline__ float hw_log2(float x) { return __builtin_amdgcn_logf(x); }
__device__ __forceinline__ float hw_exp2(float x) { return __builtin_amdgcn_exp2f(x); }
__device__ __forceinline__ float hw_rcp(float x) { return __builtin_amdgcn_rcpf(x); }

typedef int i32x4 __attribute__((ext_vector_type(4)));

__device__ __forceinline__ void gl_lds16(const void* g, void* l) {
  __builtin_amdgcn_global_load_lds(
      (const __attribute__((address_space(1))) void*)g,
      (__attribute__((address_space(3))) void*)l, 16, 0, 0);
}

#define BAR() asm volatile("s_barrier" ::: "memory")
#define VM8() asm volatile("s_waitcnt vmcnt(8)" ::: "memory")

// ---- merged row L2-normalize f32 -> int8 (x QSCALE) for BOTH tensors ----
// rows [0,B) -> xnb in FRAGMENT-MAJOR A' layout (R15-verified transform);
// rows [B,B+C) -> wnb plain row-major. One launch instead of two.
// |xn_i| <= ~0.17 -> q <= ~87 << 127; dot exact in int32 (<= 7.7M < 2^24).
__global__ __launch_bounds__(256) void k_norm_all(const float* __restrict__ x,
                                                  const float* __restrict__ w,
                                                  unsigned char* __restrict__ xnb,
                                                  unsigned char* __restrict__ wnb,
                                                  int B, int D) {
  const int r = blockIdx.x;
  const int tid = threadIdx.x;
  const bool isx = (r < B);
  const int row = isx ? r : r - B;
  const float* in = isx ? x : w;
  const float4* inr = (const float4*)(in + (size_t)row * D);
  float4 v = inr[tid];
  float ss = v.x * v.x + v.y * v.y + v.z * v.z + v.w * v.w;
#pragma unroll
  for (int off = 32; off >= 1; off >>= 1) ss += __shfl_xor(ss, off, 64);
  __shared__ float s4[4];
  if ((tid & 63) == 0) s4[tid >> 6] = ss;
  __syncthreads();
  float tot = s4[0] + s4[1] + s4[2] + s4[3];
  float scale = QSCALE / fmaxf(sqrtf(tot), 1e-12f);
  int q0 = __float2int_rn(fmaxf(-127.f, fminf(127.f, v.x * scale)));
  int q1 = __float2int_rn(fmaxf(-127.f, fminf(127.f, v.y * scale)));
  int q2 = __float2int_rn(fmaxf(-127.f, fminf(127.f, v.z * scale)));
  int q3 = __float2int_rn(fmaxf(-127.f, fminf(127.f, v.w * scale)));
  int w0 = (q0 & 0xff) | ((q1 & 0xff) << 8) | ((q2 & 0xff) << 16) | (q3 << 24);
  const int k0 = tid * 4;
  if (isx) {
    // fragment-major: (16-row,64-k) block contiguous 1KB; wave operand at +lane*16
    const size_t doff = (size_t)(row >> 4) * (16 * D) + ((k0 >> 6) << 10) +
                        (((k0 >> 4) & 3) << 8) + ((row & 15) << 4) + (k0 & 15);
    *(int*)(xnb + doff) = w0;
  } else {
    *(int*)(wnb + (size_t)row * D + k0) = w0;
  }
}

// ------- fused i8 GEMM + harmonic-softmax partials (R19 VERBATIM — best) ----
// Tile 128x256, 4 waves (2M x 2N), per-wave 64x128: acc[4][8] = 128 AGPR.
// LDS = ring-2 x 32KB B-slots = 64KB -> 2 blocks/CU (2 independent barrier
// groups). Slot = 4 proven zero-conflict 8KB chunks, one chunk staged
// entirely by one wave (8 gl_lds, rule-#21 decode verbatim).
// Ring-2 calendar (audited, R19): at top of tile t, BAR guarantees slot
// (t+1)%2's readers (tile t-1) done -> stage B(t+1) there right after BAR.
// VM8 at top certifies B(t): per tile exactly 16 VMEM issue [B(t+1) 8,
// av(t+1) 8], so the 8-newest at top of t are av(t). av = A direct from
// fragment-major global, prefetch-after-use (refill av[mm] after h=1 use);
// compiler inserts av/bv per-use waits (G7).
__global__ __launch_bounds__(256, 2) void k_gemm_lse(
    const unsigned char* __restrict__ xnb,   // fragment-major A'
    const unsigned char* __restrict__ wnb,   // plain row-major
    const int* __restrict__ tgt,
    float* __restrict__ parts,
    float* __restrict__ tlp,
    int M, int C, int D, int ntN) {
  __shared__ __align__(16) unsigned char sB[2][32768];
  __shared__ int s_tgt[128];

  const int ntM = M >> 7;               // 32
  const int nwg = ntM * ntN;            // 4000 (div by 8)
  const int orig = blockIdx.x;
  const int cpx = nwg >> 3;
  const int bid = (orig & 7) * cpx + (orig >> 3);   // bijective XCD swizzle
  const int tileM = bid % ntM;
  const int tileN = bid / ntM;
  const int row0 = tileM << 7;
  const int c0 = tileN << 8;

  const int tid = threadIdx.x;
  const int lane = tid & 63;
  const int wid = tid >> 6;             // 0..3
  const int wr = wid >> 1;              // M-half (64 rows)
  const int wc = wid & 1;               // N-half (128 cols)
  const int fcol = lane & 15;
  const int kq = lane >> 4;

  if (tid < 128) s_tgt[tid] = tgt[row0 + tid];

  // staging lane constants (rule #21 decode, R11/R13 verbatim)
  const int srow_l = lane >> 2;
  const int scol_l = (((lane & 3) ^ ((lane >> 3) & 3)) << 4);
  const int lane16 = lane << 4;
  const size_t Dz = (size_t)D;

  // wave wid stages chunk (colhalf = wid>>1, khalf = wid&1): 8 x 1KB blocks
#define STAGE_BT(ds, tt)                                                       \
  do {                                                                         \
    _Pragma("unroll") for (int q = 0; q < 8; ++q)                              \
        gl_lds16(wnb + (size_t)(c0 + ((wid >> 1) << 7) + (q << 4) + srow_l) *  \
                           Dz + (tt)*128 + ((wid & 1) << 6) + scol_l,          \
                 sB[ds] + (wid << 13) + (q << 10) + lane16);                   \
  } while (0)

  // bv read: chunk (wc, h) base + (n*16 + fcol)*64 + slot16 (zero-conflict)
  const int slot16 = ((kq ^ ((fcol >> 1) & 3)) << 4);
  const int bbase = fcol * 64 + slot16;

  // A' direct-load base (R15 verbatim); 64-k frag f at + f*1024
  const unsigned char* apan =
      xnb + (size_t)(tileM * 8 + wr * 4) * (16 * D) + lane16;

  i32x4 acc[4][8];
#pragma unroll
  for (int m = 0; m < 4; ++m)
#pragma unroll
    for (int n = 0; n < 8; ++n) acc[m][n] = (i32x4){0, 0, 0, 0};

  i32x4 av[4][2], bv[8];
  const int NT = D >> 7;  // 8 K-tiles of 128

  // prologue: stage B(0) into slot 0; issue av(0). queue = [B0 8, av0 8].
  STAGE_BT(0, 0);
#pragma unroll
  for (int mm = 0; mm < 4; ++mm)
#pragma unroll
    for (int h = 0; h < 2; ++h)
      av[mm][h] = *(const i32x4*)(apan + (size_t)mm * (16 * D) + h * 1024);

#pragma unroll
  for (int t = 0; t < 8; ++t) {
    VM8();   // 8-newest = av(t); certifies B(t) (and B(<t)) for all waves
    BAR();   // cross-wave cert; slot (t+1)&1's readers (tile t-1) done
    if (t + 1 < NT) STAGE_BT((t + 1) & 1, t + 1);
#pragma unroll
    for (int h = 0; h < 2; ++h) {
      const unsigned char* chunk = sB[t & 1] + ((wc * 2 + h) << 13);
#pragma unroll
      for (int n = 0; n < 8; ++n)
        bv[n] = *(const i32x4*)(chunk + (n << 10) + bbase);
      __builtin_amdgcn_s_setprio(1);
#pragma unroll
      for (int mm = 0; mm < 4; ++mm) {
#pragma unroll
        for (int n = 0; n < 8; ++n)
          acc[mm][n] = __builtin_amdgcn_mfma_i32_16x16x64_i8(
              av[mm][h], bv[n], acc[mm][n], 0, 0, 0);
        // after av[mm]'s LAST use (h==1): refill both halves for tile t+1
        if (h == 1 && t + 1 < NT) {
#pragma unroll
          for (int hh = 0; hh < 2; ++hh)
            av[mm][hh] = *(const i32x4*)(apan + (size_t)mm * (16 * D) +
                                         (2 * (t + 1) + hh) * 1024);
        }
      }
      __builtin_amdgcn_s_setprio(0);
    }
  }

  // ---- epilogue: t2 = 2 - 2*dot/S^2; se-term = t2^-5 = d^-10 ----
  // C/D: col = fcol, row = kq*4 + j per 16x16 fragment.
#pragma unroll
  for (int m = 0; m < 4; ++m) {
#pragma unroll
    for (int j = 0; j < 4; ++j) {
      const int rl = wr * 64 + m * 16 + kq * 4 + j;
      const int grow = row0 + rl;
      const int trow = s_tgt[rl];
      float se = 0.f;
#pragma unroll
      for (int n = 0; n < 8; ++n) {
        float dotf = (float)acc[m][n][j];
        float t2 = fmaxf(fmaf(dotf, -2.f / (QSCALE * QSCALE), 2.f), 1e-6f);
        float r = hw_rcp(t2);
        float r2 = r * r;
        float r4 = r2 * r2;
        se += r4 * r;  // t2^-5
        int col = c0 + wc * 128 + n * 16 + fcol;
        if (col == trow) tlp[grow] = (-HEXP * LN2) * hw_log2(sqrtf(t2) + 1e-8f);
      }
#pragma unroll
      for (int off = 8; off >= 1; off >>= 1) se += __shfl_xor(se, off, 64);
      if (fcol == 0) parts[(size_t)grow * (ntN * 2) + tileN * 2 + wc] = se;
    }
  }
}

// ------- per-row sum of linear partials + loss (single wave per row) -------
__global__ __launch_bounds__(64) void k_combine(const float* __restrict__ parts,
                                                const float* __restrict__ tlp,
                                                float* __restrict__ rloss, int P) {
  const int row = blockIdx.x;
  const int lane = threadIdx.x;
  const float* p = parts + (size_t)row * P;
  float s = 0.f;
  for (int i = lane; i < P; i += 64) s += p[i];
#pragma unroll
  for (int off = 32; off >= 1; off >>= 1) s += __shfl_xor(s, off, 64);
  if (lane == 0) {
    float lse = hw_log2(s) * LN2;
    float pt = hw_exp2((tlp[row] - lse) * RLN2);
    rloss[row] = -hw_log2(pt + 1e-8f) * LN2;
  }
}

// ---------------- mean over rows ----------------
__global__ __launch_bounds__(256) void k_mean(const float* __restrict__ rloss,
                                              float* __restrict__ out, int B) {
  const int tid = threadIdx.x;
  double s = 0.0;
  for (int i = tid; i < B; i += 256) s += (double)rloss[i];
#pragma unroll
  for (int off = 32; off >= 1; off >>= 1) s += __shfl_xor(s, off, 64);
  __shared__ double sd[4];
  if ((tid & 63) == 0) sd[tid >> 6] = s;
  __syncthreads();
  if (tid == 0) out[0] = (float)((sd[0] + sd[1] + sd[2] + sd[3]) / (double)B);
}

extern "C" void kernel_launch(void* const* d_in, const int* in_sizes, int n_in,
                              void* d_out, int out_size, void* d_ws, size_t ws_size,
                              hipStream_t stream) {
  const float* x = (const float*)d_in[0];
  const float* w = (const float*)d_in[1];
  const int* tg = (const int*)d_in[2];
  const int B = in_sizes[2];
  const int D = in_sizes[0] / B;       // 1024
  const int C = in_sizes[1] / D;       // 32000
  const int ntN = C / 256;             // 125

  char* ws = (char*)d_ws;
  unsigned char* xnb = (unsigned char*)ws;                   // B*D i8 (frag-major)
  unsigned char* wnb = xnb + (size_t)B * D;                  // C*D i8 (row-major)
  size_t off = (size_t)B * D + (size_t)C * D;
  off = (off + 255) & ~(size_t)255;
  float* parts = (float*)(ws + off);                         // B * ntN * 2
  off += (size_t)B * ntN * 2 * sizeof(float);
  float* tlp = (float*)(ws + off);                           // B
  off += (size_t)B * sizeof(float);
  float* rloss = (float*)(ws + off);                         // B

  k_norm_all<<<B + C, 256, 0, stream>>>(x, w, xnb, wnb, B, D);
  k_gemm_lse<<<(B / 128) * ntN, 256, 0, stream>>>(xnb, wnb, tg, parts, tlp, B, C, D, ntN);
  k_combine<<<B, 64, 0, stream>>>(parts, tlp, rloss, ntN * 2);
  k_mean<<<1, 256, 0, stream>>>(rloss, (float*)d_out, B);
}

// Round 22
// 219.620 us; speedup vs baseline: 1.1366x; 1.0108x over previous
//
#include <hip/hip_runtime.h>
#include <cstdint>

#define HEXP 10.0f
#define LN2 0.69314718056f
#define RLN2 1.44269504089f
#define QSCALE 500.0f

__device__ __forceinline__ float hw_log2(float x) { return __builtin_amdgcn_logf(x); }
__device__ __forceinline__ float hw_exp2(float x) { return __builtin_amdgcn_exp2f(x); }
__device__ __forceinline__ float hw_rcp(float x) { return __builtin_amdgcn_rcpf(x); }

typedef int i32x4 __attribute__((ext_vector_type(4)));

__device__ __forceinline__ void gl_lds16(const void* g, void* l) {
  __builtin_amdgcn_global_load_lds(
      (const __attribute__((address_space(1))) void*)g,
      (__attribute__((address_space(3))) void*)l, 16, 0, 0);
}

#define BAR() asm volatile("s_barrier" ::: "memory")
#define VM8() asm volatile("s_waitcnt vmcnt(8)" ::: "memory")

// ---- merged row L2-normalize f32 -> int8 (x QSCALE) for BOTH tensors ----
// rows [0,B) -> xnb FRAGMENT-MAJOR A'; rows [B,B+C) -> wnb row-major.
// |xn_i| <= ~0.17 -> q <= ~87 << 127; dot exact in int32 (<= 7.7M < 2^24).
__global__ __launch_bounds__(256) void k_norm_all(const float* __restrict__ x,
                                                  const float* __restrict__ w,
                                                  unsigned char* __restrict__ xnb,
                                                  unsigned char* __restrict__ wnb,
                                                  int B, int D) {
  const int r = blockIdx.x;
  const int tid = threadIdx.x;
  const bool isx = (r < B);
  const int row = isx ? r : r - B;
  const float* in = isx ? x : w;
  const float4* inr = (const float4*)(in + (size_t)row * D);
  float4 v = inr[tid];
  float ss = v.x * v.x + v.y * v.y + v.z * v.z + v.w * v.w;
#pragma unroll
  for (int off = 32; off >= 1; off >>= 1) ss += __shfl_xor(ss, off, 64);
  __shared__ float s4[4];
  if ((tid & 63) == 0) s4[tid >> 6] = ss;
  __syncthreads();
  float tot = s4[0] + s4[1] + s4[2] + s4[3];
  float scale = QSCALE / fmaxf(sqrtf(tot), 1e-12f);
  int q0 = __float2int_rn(fmaxf(-127.f, fminf(127.f, v.x * scale)));
  int q1 = __float2int_rn(fmaxf(-127.f, fminf(127.f, v.y * scale)));
  int q2 = __float2int_rn(fmaxf(-127.f, fminf(127.f, v.z * scale)));
  int q3 = __float2int_rn(fmaxf(-127.f, fminf(127.f, v.w * scale)));
  int w0 = (q0 & 0xff) | ((q1 & 0xff) << 8) | ((q2 & 0xff) << 16) | (q3 << 24);
  const int k0 = tid * 4;
  if (isx) {
    const size_t doff = (size_t)(row >> 4) * (16 * D) + ((k0 >> 6) << 10) +
                        (((k0 >> 4) & 3) << 8) + ((row & 15) << 4) + (k0 & 15);
    *(int*)(xnb + doff) = w0;
  } else {
    *(int*)(wnb + (size_t)row * D + k0) = w0;
  }
}

// ------- fused i8 GEMM + harmonic-softmax partials (R19 + K-phase stagger) ----
// R19 structure verbatim (tile 128x256, 4 waves 2Mx2N, acc[4][8]=128 AGPR,
// ring-2 32KB B-slots, VM8 count-calendar, A-direct prefetch-after-use).
// NEW: per-block K-tile ORDER rotation — block with odd `orig` starts at
// physical K-tile 4 and wraps ((tt+pofs)&7). The two co-resident blocks'
// serial segments (VM8+BAR+ds_read) then anti-align instead of phase-locking,
// so each block's MFMA covers the other's stalls. i8 dot is exact int32 ->
// accumulation order is bitwise-irrelevant; the ring-2/VM8 calendar operates
// on LOGICAL iteration indices (pure counts), untouched by the remap.
__global__ __launch_bounds__(256, 2) void k_gemm_lse(
    const unsigned char* __restrict__ xnb,   // fragment-major A'
    const unsigned char* __restrict__ wnb,   // plain row-major
    const int* __restrict__ tgt,
    float* __restrict__ parts,
    float* __restrict__ tlp,
    int M, int C, int D, int ntN) {
  __shared__ __align__(16) unsigned char sB[2][32768];
  __shared__ int s_tgt[128];

  const int ntM = M >> 7;               // 32
  const int nwg = ntM * ntN;            // 4000 (div by 8)
  const int orig = blockIdx.x;
  const int cpx = nwg >> 3;
  const int bid = (orig & 7) * cpx + (orig >> 3);   // bijective XCD swizzle
  const int tileM = bid % ntM;
  const int tileN = bid / ntM;
  const int row0 = tileM << 7;
  const int c0 = tileN << 8;
  const int pofs = (orig & 1) << 2;     // K-phase stagger: 0 or 4 (of 8)

  const int tid = threadIdx.x;
  const int lane = tid & 63;
  const int wid = tid >> 6;             // 0..3
  const int wr = wid >> 1;              // M-half (64 rows)
  const int wc = wid & 1;               // N-half (128 cols)
  const int fcol = lane & 15;
  const int kq = lane >> 4;

  if (tid < 128) s_tgt[tid] = tgt[row0 + tid];

  // staging lane constants (rule #21 decode, R11/R13 verbatim)
  const int srow_l = lane >> 2;
  const int scol_l = (((lane & 3) ^ ((lane >> 3) & 3)) << 4);
  const int lane16 = lane << 4;
  const size_t Dz = (size_t)D;

  // wave wid stages chunk (colhalf = wid>>1, khalf = wid&1): 8 x 1KB blocks.
  // tp = PHYSICAL K-tile index.
#define STAGE_BT(ds, tp)                                                       \
  do {                                                                         \
    _Pragma("unroll") for (int q = 0; q < 8; ++q)                              \
        gl_lds16(wnb + (size_t)(c0 + ((wid >> 1) << 7) + (q << 4) + srow_l) *  \
                           Dz + (tp)*128 + ((wid & 1) << 6) + scol_l,          \
                 sB[ds] + (wid << 13) + (q << 10) + lane16);                   \
  } while (0)

  // bv read: chunk (wc, h) base + (n*16 + fcol)*64 + slot16 (zero-conflict)
  const int slot16 = ((kq ^ ((fcol >> 1) & 3)) << 4);
  const int bbase = fcol * 64 + slot16;

  // A' direct-load base (R15 verbatim); 64-k frag f at + f*1024
  const unsigned char* apan =
      xnb + (size_t)(tileM * 8 + wr * 4) * (16 * D) + lane16;

  i32x4 acc[4][8];
#pragma unroll
  for (int m = 0; m < 4; ++m)
#pragma unroll
    for (int n = 0; n < 8; ++n) acc[m][n] = (i32x4){0, 0, 0, 0};

  i32x4 av[4][2], bv[8];
  const int NT = D >> 7;  // 8 K-tiles of 128

  // prologue: stage physical tile pofs into slot 0; av from physical pofs.
  STAGE_BT(0, pofs);
#pragma unroll
  for (int mm = 0; mm < 4; ++mm)
#pragma unroll
    for (int h = 0; h < 2; ++h)
      av[mm][h] = *(const i32x4*)(apan + (size_t)mm * (16 * D) +
                                  (2 * pofs + h) * 1024);

#pragma unroll
  for (int tt = 0; tt < 8; ++tt) {
    const int tpn = (tt + 1 + pofs) & 7;  // next PHYSICAL tile
    VM8();   // 8-newest = av(logical tt); certifies B(logical tt)
    BAR();   // cross-wave cert; slot (tt+1)&1's readers (tt-1) done
    if (tt + 1 < NT) STAGE_BT((tt + 1) & 1, tpn);
#pragma unroll
    for (int h = 0; h < 2; ++h) {
      const unsigned char* chunk = sB[tt & 1] + ((wc * 2 + h) << 13);
#pragma unroll
      for (int n = 0; n < 8; ++n)
        bv[n] = *(const i32x4*)(chunk + (n << 10) + bbase);
      __builtin_amdgcn_s_setprio(1);
#pragma unroll
      for (int mm = 0; mm < 4; ++mm) {
#pragma unroll
        for (int n = 0; n < 8; ++n)
          acc[mm][n] = __builtin_amdgcn_mfma_i32_16x16x64_i8(
              av[mm][h], bv[n], acc[mm][n], 0, 0, 0);
        // after av[mm]'s LAST use (h==1): refill for next physical tile
        if (h == 1 && tt + 1 < NT) {
#pragma unroll
          for (int hh = 0; hh < 2; ++hh)
            av[mm][hh] = *(const i32x4*)(apan + (size_t)mm * (16 * D) +
                                         (2 * tpn + hh) * 1024);
        }
      }
      __builtin_amdgcn_s_setprio(0);
    }
  }

  // ---- epilogue: t2 = 2 - 2*dot/S^2; se-term = t2^-5 = d^-10 ----
  // C/D: col = fcol, row = kq*4 + j per 16x16 fragment.
#pragma unroll
  for (int m = 0; m < 4; ++m) {
#pragma unroll
    for (int j = 0; j < 4; ++j) {
      const int rl = wr * 64 + m * 16 + kq * 4 + j;
      const int grow = row0 + rl;
      const int trow = s_tgt[rl];
      float se = 0.f;
#pragma unroll
      for (int n = 0; n < 8; ++n) {
        float dotf = (float)acc[m][n][j];
        float t2 = fmaxf(fmaf(dotf, -2.f / (QSCALE * QSCALE), 2.f), 1e-6f);
        float r = hw_rcp(t2);
        float r2 = r * r;
        float r4 = r2 * r2;
        se += r4 * r;  // t2^-5
        int col = c0 + wc * 128 + n * 16 + fcol;
        if (col == trow) tlp[grow] = (-HEXP * LN2) * hw_log2(sqrtf(t2) + 1e-8f);
      }
#pragma unroll
      for (int off = 8; off >= 1; off >>= 1) se += __shfl_xor(se, off, 64);
      if (fcol == 0) parts[(size_t)grow * (ntN * 2) + tileN * 2 + wc] = se;
    }
  }
}

// ------- per-row sum of linear partials + loss (single wave per row) -------
__global__ __launch_bounds__(64) void k_combine(const float* __restrict__ parts,
                                                const float* __restrict__ tlp,
                                                float* __restrict__ rloss, int P) {
  const int row = blockIdx.x;
  const int lane = threadIdx.x;
  const float* p = parts + (size_t)row * P;
  float s = 0.f;
  for (int i = lane; i < P; i += 64) s += p[i];
#pragma unroll
  for (int off = 32; off >= 1; off >>= 1) s += __shfl_xor(s, off, 64);
  if (lane == 0) {
    float lse = hw_log2(s) * LN2;
    float pt = hw_exp2((tlp[row] - lse) * RLN2);
    rloss[row] = -hw_log2(pt + 1e-8f) * LN2;
  }
}

// ---------------- mean over rows ----------------
__global__ __launch_bounds__(256) void k_mean(const float* __restrict__ rloss,
                                              float* __restrict__ out, int B) {
  const int tid = threadIdx.x;
  double s = 0.0;
  for (int i = tid; i < B; i += 256) s += (double)rloss[i];
#pragma unroll
  for (int off = 32; off >= 1; off >>= 1) s += __shfl_xor(s, off, 64);
  __shared__ double sd[4];
  if ((tid & 63) == 0) sd[tid >> 6] = s;
  __syncthreads();
  if (tid == 0) out[0] = (float)((sd[0] + sd[1] + sd[2] + sd[3]) / (double)B);
}

extern "C" void kernel_launch(void* const* d_in, const int* in_sizes, int n_in,
                              void* d_out, int out_size, void* d_ws, size_t ws_size,
                              hipStream_t stream) {
  const float* x = (const float*)d_in[0];
  const float* w = (const float*)d_in[1];
  const int* tg = (const int*)d_in[2];
  const int B = in_sizes[2];
  const int D = in_sizes[0] / B;       // 1024
  const int C = in_sizes[1] / D;       // 32000
  const int ntN = C / 256;             // 125

  char* ws = (char*)d_ws;
  unsigned char* xnb = (unsigned char*)ws;                   // B*D i8 (frag-major)
  unsigned char* wnb = xnb + (size_t)B * D;                  // C*D i8 (row-major)
  size_t off = (size_t)B * D + (size_t)C * D;
  off = (off + 255) & ~(size_t)255;
  float* parts = (float*)(ws + off);                         // B * ntN * 2
  off += (size_t)B * ntN * 2 * sizeof(float);
  float* tlp = (float*)(ws + off);                           // B
  off += (size_t)B * sizeof(float);
  float* rloss = (float*)(ws + off);                         // B

  k_norm_all<<<B + C, 256, 0, stream>>>(x, w, xnb, wnb, B, D);
  k_gemm_lse<<<(B / 128) * ntN, 256, 0, stream>>>(xnb, wnb, tg, parts, tlp, B, C, D, ntN);
  k_combine<<<B, 64, 0, stream>>>(parts, tlp, rloss, ntN * 2);
  k_mean<<<1, 256, 0, stream>>>(rloss, (float*)d_out, B);
}